// Round 2
// baseline (603.680 us; speedup 1.0000x reference)
//
#include <hip/hip_runtime.h>
#include <hip/hip_bf16.h>
#include <math.h>

// ---------------------------------------------------------------------------
// 3-layer GCN (PyG GCNConv semantics) on MI355X.
// Strategy:
//   preprocessing (once per call):
//     deg[i] = 1 + sum_{e: dst=i} w[e];  dinv = 1/sqrt(deg)
//     CSR by dst (count -> scan -> fill), norm[e] = dinv[src]*w*dinv[dst]
//   per layer:
//     H = X @ W           (64-wide fp32 tiled GEMM, W in LDS)
//     out[i] = relu( sum_{e in(i)} H[src_e]*norm_e + H[i]*dinv[i]^2 + b )
//              (one wave per node, lane = feature)
// ---------------------------------------------------------------------------

__global__ __launch_bounds__(256) void init_node_k(float* deg, int* cnt, int* fill, int N) {
    int i = blockIdx.x * blockDim.x + threadIdx.x;
    if (i < N) { deg[i] = 1.0f; cnt[i] = 0; fill[i] = 0; }
}

__global__ __launch_bounds__(256) void deg_count_k(const int* __restrict__ dst,
                                                   const float* __restrict__ w,
                                                   float* deg, int* cnt, int E) {
    int e = blockIdx.x * blockDim.x + threadIdx.x;
    if (e < E) {
        int d = dst[e];
        atomicAdd(&deg[d], w[e]);
        atomicAdd(&cnt[d], 1);
    }
}

__global__ __launch_bounds__(256) void dinv_k(const float* __restrict__ deg, float* dinv, int N) {
    int i = blockIdx.x * blockDim.x + threadIdx.x;
    if (i < N) {
        float d = deg[i];
        dinv[i] = (d > 0.0f) ? (1.0f / sqrtf(d)) : 0.0f;
    }
}

// ---- exclusive scan of cnt[0..N) into rowptr[0..N), rowptr[N]=total ----
__global__ __launch_bounds__(1024) void scan_block_k(const int* __restrict__ cnt,
                                                     int* __restrict__ tmp,
                                                     int* __restrict__ bsum, int N) {
    __shared__ int sm[1024];
    int tid = threadIdx.x;
    int g = blockIdx.x * 1024 + tid;
    int v = (g < N) ? cnt[g] : 0;
    sm[tid] = v;
    __syncthreads();
    for (int off = 1; off < 1024; off <<= 1) {
        int t = (tid >= off) ? sm[tid - off] : 0;
        __syncthreads();
        sm[tid] += t;
        __syncthreads();
    }
    if (g < N) tmp[g] = sm[tid] - v;          // exclusive within block
    if (tid == 1023) bsum[blockIdx.x] = sm[1023];
}

__global__ void scan_bsums_k(int* bsum, int nb, int* rowptr, int N) {
    // single thread: nb ~ 98 elements
    int run = 0;
    for (int i = 0; i < nb; ++i) { int t = bsum[i]; bsum[i] = run; run += t; }
    rowptr[N] = run;
}

__global__ __launch_bounds__(1024) void scan_add_k(const int* __restrict__ tmp,
                                                   const int* __restrict__ bsum,
                                                   int* __restrict__ rowptr, int N) {
    int g = blockIdx.x * 1024 + threadIdx.x;
    if (g < N) rowptr[g] = tmp[g] + bsum[blockIdx.x];
}

__global__ __launch_bounds__(256) void fill_csr_k(const int* __restrict__ src,
                                                  const int* __restrict__ dst,
                                                  const float* __restrict__ w,
                                                  const float* __restrict__ dinv,
                                                  const int* __restrict__ rowptr,
                                                  int* fill,
                                                  int* __restrict__ csrc,
                                                  float* __restrict__ cnorm, int E) {
    int e = blockIdx.x * blockDim.x + threadIdx.x;
    if (e < E) {
        int d = dst[e];
        int s = src[e];
        int pos = rowptr[d] + atomicAdd(&fill[d], 1);
        csrc[pos] = s;
        cnorm[pos] = dinv[s] * w[e] * dinv[d];
    }
}

// ---- GEMM: H[N,64] = X[N,64] @ W[64,64] (fp32, no MFMA on CDNA4) ----
// block = 256 threads, 64-row tile. W + padded X tile in LDS.
// thread (tc=tid&15, tr=tid>>4) computes 4 rows x 4 cols micro-tile.
__global__ __launch_bounds__(256) void gemm64_k(const float* __restrict__ X,
                                                const float* __restrict__ W,
                                                float* __restrict__ H, int N) {
    __shared__ float Wl[64 * 64];   // row-major W[k][c]
    __shared__ float Xl[64 * 68];   // X[row][k], stride 68 (bank-spread)
    int tid = threadIdx.x;
    for (int i = tid; i < 4096; i += 256) Wl[i] = W[i];
    int row0 = blockIdx.x * 64;
    {
        int r = tid >> 6, c = tid & 63;
        #pragma unroll
        for (int p = 0; p < 16; ++p) {
            int rr = r + 4 * p;
            int grow = row0 + rr;
            Xl[rr * 68 + c] = (grow < N) ? X[(size_t)grow * 64 + c] : 0.0f;
        }
    }
    __syncthreads();
    int tc = tid & 15, tr = tid >> 4;
    float acc[4][4];
    #pragma unroll
    for (int i = 0; i < 4; ++i)
        #pragma unroll
        for (int j = 0; j < 4; ++j) acc[i][j] = 0.0f;

    #pragma unroll 8
    for (int k = 0; k < 64; ++k) {
        float4 wv = *(const float4*)&Wl[k * 64 + 4 * tc];
        float x0 = Xl[(4 * tr + 0) * 68 + k];
        float x1 = Xl[(4 * tr + 1) * 68 + k];
        float x2 = Xl[(4 * tr + 2) * 68 + k];
        float x3 = Xl[(4 * tr + 3) * 68 + k];
        acc[0][0] += x0 * wv.x; acc[0][1] += x0 * wv.y; acc[0][2] += x0 * wv.z; acc[0][3] += x0 * wv.w;
        acc[1][0] += x1 * wv.x; acc[1][1] += x1 * wv.y; acc[1][2] += x1 * wv.z; acc[1][3] += x1 * wv.w;
        acc[2][0] += x2 * wv.x; acc[2][1] += x2 * wv.y; acc[2][2] += x2 * wv.z; acc[2][3] += x2 * wv.w;
        acc[3][0] += x3 * wv.x; acc[3][1] += x3 * wv.y; acc[3][2] += x3 * wv.z; acc[3][3] += x3 * wv.w;
    }
    #pragma unroll
    for (int i = 0; i < 4; ++i) {
        int grow = row0 + 4 * tr + i;
        if (grow < N) {
            float4 st = make_float4(acc[i][0], acc[i][1], acc[i][2], acc[i][3]);
            *(float4*)&H[(size_t)grow * 64 + 4 * tc] = st;
        }
    }
}

// ---- aggregation: one wave per node, lane = feature (D=64) ----
__global__ __launch_bounds__(256) void agg_k(const float* __restrict__ H,
                                             const int* __restrict__ rowptr,
                                             const int* __restrict__ csrc,
                                             const float* __restrict__ cnorm,
                                             const float* __restrict__ dinv,
                                             const float* __restrict__ bias,
                                             float* __restrict__ out, int N) {
    int wave = (blockIdx.x * blockDim.x + threadIdx.x) >> 6;
    int lane = threadIdx.x & 63;
    if (wave >= N) return;
    int i = wave;
    float di = dinv[i];
    float acc = H[(size_t)i * 64 + lane] * (di * di);   // self loop, norm = dinv^2
    int e0 = rowptr[i], e1 = rowptr[i + 1];
    int e = e0;
    while (e < e1) {
        int nb = e1 - e;
        if (nb > 64) nb = 64;
        int   s  = (lane < nb) ? csrc[e + lane]  : 0;
        float nm = (lane < nb) ? cnorm[e + lane] : 0.0f;
        #pragma unroll 4
        for (int j = 0; j < nb; ++j) {
            int   sj = __shfl(s, j);
            float nj = __shfl(nm, j);
            acc += H[(size_t)sj * 64 + lane] * nj;
        }
        e += nb;
    }
    float v = acc + bias[lane];
    out[(size_t)i * 64 + lane] = fmaxf(v, 0.0f);
}

// ---------------------------------------------------------------------------

extern "C" void kernel_launch(void* const* d_in, const int* in_sizes, int n_in,
                              void* d_out, int out_size, void* d_ws, size_t ws_size,
                              hipStream_t stream) {
    const float* x   = (const float*)d_in[0];
    const int*   ei  = (const int*)d_in[1];
    const float* ew  = (const float*)d_in[2];
    const float* W1  = (const float*)d_in[3];
    const float* b1  = (const float*)d_in[4];
    const float* W2  = (const float*)d_in[5];
    const float* b2  = (const float*)d_in[6];
    const float* W3  = (const float*)d_in[7];
    const float* b3  = (const float*)d_in[8];
    float* out = (float*)d_out;

    const int N = in_sizes[0] / 64;         // 100000
    const int E = in_sizes[1] / 2;          // 1200000
    const int* src = ei;
    const int* dst = ei + E;

    // ---- workspace carve-up (all 256B-aligned) ----
    char* p = (char*)d_ws;
    size_t off = 0;
    auto carve = [&](size_t bytes) -> void* {
        void* q = p + off;
        off += (bytes + 255) & ~(size_t)255;
        return q;
    };
    float* deg    = (float*)carve((size_t)N * 4);
    float* dinv   = (float*)carve((size_t)N * 4);
    int*   cnt    = (int*)  carve((size_t)N * 4);
    int*   tmp    = (int*)  carve((size_t)N * 4);
    int*   fill   = (int*)  carve((size_t)N * 4);
    int*   rowptr = (int*)  carve((size_t)(N + 1) * 4);
    int*   bsum   = (int*)  carve((size_t)1024 * 4);
    int*   csrc   = (int*)  carve((size_t)E * 4);
    float* cnorm  = (float*)carve((size_t)E * 4);
    float* Hbuf   = (float*)carve((size_t)N * 64 * 4);
    float* Abuf   = (float*)carve((size_t)N * 64 * 4);
    (void)ws_size;

    const int nB  = (N + 255) / 256;
    const int eB  = (E + 255) / 256;
    const int nb  = (N + 1023) / 1024;              // scan blocks
    const int gB  = (N + 63) / 64;                  // gemm blocks (64 rows each)
    const int aB  = (N * 64 + 255) / 256;           // agg blocks (4 waves each)

    // preprocessing
    init_node_k<<<nB, 256, 0, stream>>>(deg, cnt, fill, N);
    deg_count_k<<<eB, 256, 0, stream>>>(dst, ew, deg, cnt, E);
    dinv_k<<<nB, 256, 0, stream>>>(deg, dinv, N);
    scan_block_k<<<nb, 1024, 0, stream>>>(cnt, tmp, bsum, N);
    scan_bsums_k<<<1, 1, 0, stream>>>(bsum, nb, rowptr, N);
    scan_add_k<<<nb, 1024, 0, stream>>>(tmp, bsum, rowptr, N);
    fill_csr_k<<<eB, 256, 0, stream>>>(src, dst, ew, dinv, rowptr, fill, csrc, cnorm, E);

    // layer 1: H = x @ W1 ; A = relu(agg(H) + b1)
    gemm64_k<<<gB, 256, 0, stream>>>(x, W1, Hbuf, N);
    agg_k<<<aB, 256, 0, stream>>>(Hbuf, rowptr, csrc, cnorm, dinv, b1, Abuf, N);
    // layer 2
    gemm64_k<<<gB, 256, 0, stream>>>(Abuf, W2, Hbuf, N);
    agg_k<<<aB, 256, 0, stream>>>(Hbuf, rowptr, csrc, cnorm, dinv, b2, Abuf, N);
    // layer 3 -> d_out
    gemm64_k<<<gB, 256, 0, stream>>>(Abuf, W3, Hbuf, N);
    agg_k<<<aB, 256, 0, stream>>>(Hbuf, rowptr, csrc, cnorm, dinv, b3, out, N);
}

// Round 4
// 541.743 us; speedup vs baseline: 1.1143x; 1.1143x over previous
//
#include <hip/hip_runtime.h>
#include <hip/hip_bf16.h>
#include <math.h>

// ---------------------------------------------------------------------------
// 3-layer GCN (PyG GCNConv semantics) on MI355X.
//   Round-2 change: device atomics are memory-side on gfx950 (L2-bypassing
//   RMW, ~32B HBM transaction each — rocprof: deg_count WRITE_SIZE 75MB).
//   -> one packed u64 atomic per edge (cnt<<44 | wsum in 2^-32 fixed point)
//   -> CSR entries packed int2 {src, norm} (one 8B store, one array)
//   -> dinv fused into the scan's first pass; parallel aux scan
// ---------------------------------------------------------------------------

#define MASK44 ((1ull << 44) - 1)

__global__ __launch_bounds__(256) void init_k(unsigned long long* packed, int* fill, int N) {
    int i = blockIdx.x * blockDim.x + threadIdx.x;
    if (i < N) { packed[i] = 0ull; fill[i] = 0; }
}

// one packed atomic per edge: (1<<44) + w * 2^32
__global__ __launch_bounds__(256) void edge_pass_k(const int* __restrict__ dst,
                                                   const float* __restrict__ w,
                                                   unsigned long long* __restrict__ packed,
                                                   int E) {
    int t = blockIdx.x * blockDim.x + threadIdx.x;
    int e = t * 4;
    if (e + 3 < E) {
        int4   d4 = *(const int4*)(dst + e);
        float4 w4 = *(const float4*)(w + e);
        atomicAdd(&packed[d4.x], (1ull << 44) + (unsigned long long)((double)w4.x * 4294967296.0));
        atomicAdd(&packed[d4.y], (1ull << 44) + (unsigned long long)((double)w4.y * 4294967296.0));
        atomicAdd(&packed[d4.z], (1ull << 44) + (unsigned long long)((double)w4.z * 4294967296.0));
        atomicAdd(&packed[d4.w], (1ull << 44) + (unsigned long long)((double)w4.w * 4294967296.0));
    } else {
        for (int k = e; k < E; ++k)
            atomicAdd(&packed[dst[k]], (1ull << 44) + (unsigned long long)((double)w[k] * 4294967296.0));
    }
}

// block-level exclusive scan of counts (from packed) + fused dinv computation
__global__ __launch_bounds__(1024) void scan_block_k(const unsigned long long* __restrict__ packed,
                                                     float* __restrict__ dinv,
                                                     int* __restrict__ tmp,
                                                     int* __restrict__ bsum, int N) {
    __shared__ int sm[1024];
    int tid = threadIdx.x;
    int g = blockIdx.x * 1024 + tid;
    unsigned long long pk = (g < N) ? packed[g] : 0ull;
    int v = (int)(pk >> 44);
    if (g < N) {
        double deg = 1.0 + (double)(pk & MASK44) * (1.0 / 4294967296.0);   // >= 1 always
        dinv[g] = (float)(1.0 / sqrt(deg));
    }
    sm[tid] = v;
    __syncthreads();
    for (int off = 1; off < 1024; off <<= 1) {
        int t = (tid >= off) ? sm[tid - off] : 0;
        __syncthreads();
        sm[tid] += t;
        __syncthreads();
    }
    if (g < N) tmp[g] = sm[tid] - v;          // exclusive within block
    if (tid == 1023) bsum[blockIdx.x] = sm[1023];
}

// single-block parallel exclusive scan of the (<=1024) block sums
__global__ __launch_bounds__(1024) void scan_bsums_k(int* bsum, int nb, int* rowptr, int N) {
    __shared__ int sm[1024];
    int tid = threadIdx.x;
    int v = (tid < nb) ? bsum[tid] : 0;
    sm[tid] = v;
    __syncthreads();
    for (int off = 1; off < 1024; off <<= 1) {
        int t = (tid >= off) ? sm[tid - off] : 0;
        __syncthreads();
        sm[tid] += t;
        __syncthreads();
    }
    if (tid < nb) bsum[tid] = sm[tid] - v;
    if (tid == 1023) rowptr[N] = sm[1023];
}

__global__ __launch_bounds__(1024) void scan_add_k(const int* __restrict__ tmp,
                                                   const int* __restrict__ bsum,
                                                   int* __restrict__ rowptr, int N) {
    int g = blockIdx.x * 1024 + threadIdx.x;
    if (g < N) rowptr[g] = tmp[g] + bsum[blockIdx.x];
}

// CSR fill: 4 edges per thread (4 independent atomic round-trips in flight),
// packed int2 {src, norm} single 8B store.
__global__ __launch_bounds__(256) void fill_csr_k(const int* __restrict__ src,
                                                  const int* __restrict__ dst,
                                                  const float* __restrict__ w,
                                                  const float* __restrict__ dinv,
                                                  const int* __restrict__ rowptr,
                                                  int* fill,
                                                  int2* __restrict__ csr, int E) {
    int t = blockIdx.x * blockDim.x + threadIdx.x;
    int e = t * 4;
    if (e + 3 < E) {
        int4   s4 = *(const int4*)(src + e);
        int4   d4 = *(const int4*)(dst + e);
        float4 w4 = *(const float4*)(w + e);
        int p0 = rowptr[d4.x] + atomicAdd(&fill[d4.x], 1);
        int p1 = rowptr[d4.y] + atomicAdd(&fill[d4.y], 1);
        int p2 = rowptr[d4.z] + atomicAdd(&fill[d4.z], 1);
        int p3 = rowptr[d4.w] + atomicAdd(&fill[d4.w], 1);
        csr[p0] = make_int2(s4.x, __float_as_int(dinv[s4.x] * w4.x * dinv[d4.x]));
        csr[p1] = make_int2(s4.y, __float_as_int(dinv[s4.y] * w4.y * dinv[d4.y]));
        csr[p2] = make_int2(s4.z, __float_as_int(dinv[s4.z] * w4.z * dinv[d4.z]));
        csr[p3] = make_int2(s4.w, __float_as_int(dinv[s4.w] * w4.w * dinv[d4.w]));
    } else {
        for (int k = e; k < E; ++k) {
            int d = dst[k], s = src[k];
            int pos = rowptr[d] + atomicAdd(&fill[d], 1);
            csr[pos] = make_int2(s, __float_as_int(dinv[s] * w[k] * dinv[d]));
        }
    }
}

// ---- GEMM: H[N,64] = X[N,64] @ W[64,64] (fp32, no MFMA on CDNA4) ----
__global__ __launch_bounds__(256) void gemm64_k(const float* __restrict__ X,
                                                const float* __restrict__ W,
                                                float* __restrict__ H, int N) {
    __shared__ float Wl[64 * 64];   // row-major W[k][c]
    __shared__ float Xl[64 * 68];   // X[row][k], stride 68 (bank-spread)
    int tid = threadIdx.x;
    for (int i = tid; i < 4096; i += 256) Wl[i] = W[i];
    int row0 = blockIdx.x * 64;
    {
        int r = tid >> 6, c = tid & 63;
        #pragma unroll
        for (int p = 0; p < 16; ++p) {
            int rr = r + 4 * p;
            int grow = row0 + rr;
            Xl[rr * 68 + c] = (grow < N) ? X[(size_t)grow * 64 + c] : 0.0f;
        }
    }
    __syncthreads();
    int tc = tid & 15, tr = tid >> 4;
    float acc[4][4];
    #pragma unroll
    for (int i = 0; i < 4; ++i)
        #pragma unroll
        for (int j = 0; j < 4; ++j) acc[i][j] = 0.0f;

    #pragma unroll 8
    for (int k = 0; k < 64; ++k) {
        float4 wv = *(const float4*)&Wl[k * 64 + 4 * tc];
        float x0 = Xl[(4 * tr + 0) * 68 + k];
        float x1 = Xl[(4 * tr + 1) * 68 + k];
        float x2 = Xl[(4 * tr + 2) * 68 + k];
        float x3 = Xl[(4 * tr + 3) * 68 + k];
        acc[0][0] += x0 * wv.x; acc[0][1] += x0 * wv.y; acc[0][2] += x0 * wv.z; acc[0][3] += x0 * wv.w;
        acc[1][0] += x1 * wv.x; acc[1][1] += x1 * wv.y; acc[1][2] += x1 * wv.z; acc[1][3] += x1 * wv.w;
        acc[2][0] += x2 * wv.x; acc[2][1] += x2 * wv.y; acc[2][2] += x2 * wv.z; acc[2][3] += x2 * wv.w;
        acc[3][0] += x3 * wv.x; acc[3][1] += x3 * wv.y; acc[3][2] += x3 * wv.z; acc[3][3] += x3 * wv.w;
    }
    #pragma unroll
    for (int i = 0; i < 4; ++i) {
        int grow = row0 + 4 * tr + i;
        if (grow < N) {
            float4 st = make_float4(acc[i][0], acc[i][1], acc[i][2], acc[i][3]);
            *(float4*)&H[(size_t)grow * 64 + 4 * tc] = st;
        }
    }
}

// ---- aggregation: one wave per node, lane = feature (D=64) ----
__global__ __launch_bounds__(256) void agg_k(const float* __restrict__ H,
                                             const int* __restrict__ rowptr,
                                             const int2* __restrict__ csr,
                                             const float* __restrict__ dinv,
                                             const float* __restrict__ bias,
                                             float* __restrict__ out, int N) {
    int wave = (blockIdx.x * blockDim.x + threadIdx.x) >> 6;
    int lane = threadIdx.x & 63;
    if (wave >= N) return;
    int i = wave;
    float bi = bias[lane];
    float di = dinv[i];
    float acc = H[(size_t)i * 64 + lane] * (di * di);   // self loop, norm = dinv^2
    int e0 = rowptr[i], e1 = rowptr[i + 1];
    int e = e0;
    while (e < e1) {
        int nb = e1 - e;
        if (nb > 64) nb = 64;
        int2 m = (lane < nb) ? csr[e + lane] : make_int2(0, 0);
        #pragma unroll 4
        for (int j = 0; j < nb; ++j) {
            int   sj = __shfl(m.x, j);
            float nj = __shfl(__int_as_float(m.y), j);
            acc += H[(size_t)sj * 64 + lane] * nj;
        }
        e += nb;
    }
    out[(size_t)i * 64 + lane] = fmaxf(acc + bi, 0.0f);
}

// ---------------------------------------------------------------------------

extern "C" void kernel_launch(void* const* d_in, const int* in_sizes, int n_in,
                              void* d_out, int out_size, void* d_ws, size_t ws_size,
                              hipStream_t stream) {
    const float* x   = (const float*)d_in[0];
    const int*   ei  = (const int*)d_in[1];
    const float* ew  = (const float*)d_in[2];
    const float* W1  = (const float*)d_in[3];
    const float* b1  = (const float*)d_in[4];
    const float* W2  = (const float*)d_in[5];
    const float* b2  = (const float*)d_in[6];
    const float* W3  = (const float*)d_in[7];
    const float* b3  = (const float*)d_in[8];
    float* out = (float*)d_out;

    const int N = in_sizes[0] / 64;         // 100000
    const int E = in_sizes[1] / 2;          // 1200000
    const int* src = ei;
    const int* dst = ei + E;

    // ---- workspace carve-up (all 256B-aligned) ----
    char* p = (char*)d_ws;
    size_t off = 0;
    auto carve = [&](size_t bytes) -> void* {
        void* q = p + off;
        off += (bytes + 255) & ~(size_t)255;
        return q;
    };
    unsigned long long* packed = (unsigned long long*)carve((size_t)N * 8);
    float* dinv   = (float*)carve((size_t)N * 4);
    int*   tmp    = (int*)  carve((size_t)N * 4);
    int*   fill   = (int*)  carve((size_t)N * 4);
    int*   rowptr = (int*)  carve((size_t)(N + 1) * 4);
    int*   bsum   = (int*)  carve((size_t)1024 * 4);
    int2*  csr    = (int2*) carve((size_t)E * 8);
    float* Hbuf   = (float*)carve((size_t)N * 64 * 4);
    float* Abuf   = (float*)carve((size_t)N * 64 * 4);
    (void)ws_size;

    const int nB  = (N + 255) / 256;
    const int e4B = ((E + 3) / 4 + 255) / 256;      // 4 edges/thread
    const int nb  = (N + 1023) / 1024;              // scan blocks (98 for N=100K)
    const int gB  = (N + 63) / 64;                  // gemm blocks (64 rows each)
    const int aB  = (N * 64 + 255) / 256;           // agg blocks (4 waves each)

    // preprocessing
    init_k<<<nB, 256, 0, stream>>>(packed, fill, N);
    edge_pass_k<<<e4B, 256, 0, stream>>>(dst, ew, packed, E);
    scan_block_k<<<nb, 1024, 0, stream>>>(packed, dinv, tmp, bsum, N);
    scan_bsums_k<<<1, 1024, 0, stream>>>(bsum, nb, rowptr, N);
    scan_add_k<<<nb, 1024, 0, stream>>>(tmp, bsum, rowptr, N);
    fill_csr_k<<<e4B, 256, 0, stream>>>(src, dst, ew, dinv, rowptr, fill, csr, E);

    // layer 1: H = x @ W1 ; A = relu(agg(H) + b1)
    gemm64_k<<<gB, 256, 0, stream>>>(x, W1, Hbuf, N);
    agg_k<<<aB, 256, 0, stream>>>(Hbuf, rowptr, csr, dinv, b1, Abuf, N);
    // layer 2
    gemm64_k<<<gB, 256, 0, stream>>>(Abuf, W2, Hbuf, N);
    agg_k<<<aB, 256, 0, stream>>>(Hbuf, rowptr, csr, dinv, b2, Abuf, N);
    // layer 3 -> d_out
    gemm64_k<<<gB, 256, 0, stream>>>(Abuf, W3, Hbuf, N);
    agg_k<<<aB, 256, 0, stream>>>(Hbuf, rowptr, csr, dinv, b3, out, N);
}

// Round 5
// 451.077 us; speedup vs baseline: 1.3383x; 1.2010x over previous
//
#include <hip/hip_runtime.h>
#include <hip/hip_bf16.h>
#include <math.h>

// ---------------------------------------------------------------------------
// 3-layer GCN (PyG GCNConv semantics) on MI355X.
//   R2: packed u64 atomic per edge for degree (memory-side atomics halved).
//   R4: agg_k restructured for gather ILP — latency-bound per rocprof
//       (83us, 2.15TB/s=34% achievable, VALU 21%): 4 edges/iter via 16-lane
//       groups, float4 row loads, unroll 4 -> 16 rows in flight (was 4).
// ---------------------------------------------------------------------------

#define MASK44 ((1ull << 44) - 1)

__global__ __launch_bounds__(256) void init_k(unsigned long long* packed, int* fill, int N) {
    int i = blockIdx.x * blockDim.x + threadIdx.x;
    if (i < N) { packed[i] = 0ull; fill[i] = 0; }
}

// one packed atomic per edge: (1<<44) + w * 2^32
__global__ __launch_bounds__(256) void edge_pass_k(const int* __restrict__ dst,
                                                   const float* __restrict__ w,
                                                   unsigned long long* __restrict__ packed,
                                                   int E) {
    int t = blockIdx.x * blockDim.x + threadIdx.x;
    int e = t * 4;
    if (e + 3 < E) {
        int4   d4 = *(const int4*)(dst + e);
        float4 w4 = *(const float4*)(w + e);
        atomicAdd(&packed[d4.x], (1ull << 44) + (unsigned long long)((double)w4.x * 4294967296.0));
        atomicAdd(&packed[d4.y], (1ull << 44) + (unsigned long long)((double)w4.y * 4294967296.0));
        atomicAdd(&packed[d4.z], (1ull << 44) + (unsigned long long)((double)w4.z * 4294967296.0));
        atomicAdd(&packed[d4.w], (1ull << 44) + (unsigned long long)((double)w4.w * 4294967296.0));
    } else {
        for (int k = e; k < E; ++k)
            atomicAdd(&packed[dst[k]], (1ull << 44) + (unsigned long long)((double)w[k] * 4294967296.0));
    }
}

// block-level exclusive scan of counts (from packed) + fused dinv computation
__global__ __launch_bounds__(1024) void scan_block_k(const unsigned long long* __restrict__ packed,
                                                     float* __restrict__ dinv,
                                                     int* __restrict__ tmp,
                                                     int* __restrict__ bsum, int N) {
    __shared__ int sm[1024];
    int tid = threadIdx.x;
    int g = blockIdx.x * 1024 + tid;
    unsigned long long pk = (g < N) ? packed[g] : 0ull;
    int v = (int)(pk >> 44);
    if (g < N) {
        double deg = 1.0 + (double)(pk & MASK44) * (1.0 / 4294967296.0);   // >= 1 always
        dinv[g] = (float)(1.0 / sqrt(deg));
    }
    sm[tid] = v;
    __syncthreads();
    for (int off = 1; off < 1024; off <<= 1) {
        int t = (tid >= off) ? sm[tid - off] : 0;
        __syncthreads();
        sm[tid] += t;
        __syncthreads();
    }
    if (g < N) tmp[g] = sm[tid] - v;          // exclusive within block
    if (tid == 1023) bsum[blockIdx.x] = sm[1023];
}

// single-block parallel exclusive scan of the (<=1024) block sums
__global__ __launch_bounds__(1024) void scan_bsums_k(int* bsum, int nb, int* rowptr, int N) {
    __shared__ int sm[1024];
    int tid = threadIdx.x;
    int v = (tid < nb) ? bsum[tid] : 0;
    sm[tid] = v;
    __syncthreads();
    for (int off = 1; off < 1024; off <<= 1) {
        int t = (tid >= off) ? sm[tid - off] : 0;
        __syncthreads();
        sm[tid] += t;
        __syncthreads();
    }
    if (tid < nb) bsum[tid] = sm[tid] - v;
    if (tid == 1023) rowptr[N] = sm[1023];
}

__global__ __launch_bounds__(1024) void scan_add_k(const int* __restrict__ tmp,
                                                   const int* __restrict__ bsum,
                                                   int* __restrict__ rowptr, int N) {
    int g = blockIdx.x * 1024 + threadIdx.x;
    if (g < N) rowptr[g] = tmp[g] + bsum[blockIdx.x];
}

// CSR fill: 4 edges per thread (4 independent atomic round-trips in flight),
// packed int2 {src, norm} single 8B store.
__global__ __launch_bounds__(256) void fill_csr_k(const int* __restrict__ src,
                                                  const int* __restrict__ dst,
                                                  const float* __restrict__ w,
                                                  const float* __restrict__ dinv,
                                                  const int* __restrict__ rowptr,
                                                  int* fill,
                                                  int2* __restrict__ csr, int E) {
    int t = blockIdx.x * blockDim.x + threadIdx.x;
    int e = t * 4;
    if (e + 3 < E) {
        int4   s4 = *(const int4*)(src + e);
        int4   d4 = *(const int4*)(dst + e);
        float4 w4 = *(const float4*)(w + e);
        int p0 = rowptr[d4.x] + atomicAdd(&fill[d4.x], 1);
        int p1 = rowptr[d4.y] + atomicAdd(&fill[d4.y], 1);
        int p2 = rowptr[d4.z] + atomicAdd(&fill[d4.z], 1);
        int p3 = rowptr[d4.w] + atomicAdd(&fill[d4.w], 1);
        csr[p0] = make_int2(s4.x, __float_as_int(dinv[s4.x] * w4.x * dinv[d4.x]));
        csr[p1] = make_int2(s4.y, __float_as_int(dinv[s4.y] * w4.y * dinv[d4.y]));
        csr[p2] = make_int2(s4.z, __float_as_int(dinv[s4.z] * w4.z * dinv[d4.z]));
        csr[p3] = make_int2(s4.w, __float_as_int(dinv[s4.w] * w4.w * dinv[d4.w]));
    } else {
        for (int k = e; k < E; ++k) {
            int d = dst[k], s = src[k];
            int pos = rowptr[d] + atomicAdd(&fill[d], 1);
            csr[pos] = make_int2(s, __float_as_int(dinv[s] * w[k] * dinv[d]));
        }
    }
}

// ---- GEMM: H[N,64] = X[N,64] @ W[64,64] (fp32, no MFMA on CDNA4) ----
__global__ __launch_bounds__(256) void gemm64_k(const float* __restrict__ X,
                                                const float* __restrict__ W,
                                                float* __restrict__ H, int N) {
    __shared__ float Wl[64 * 64];   // row-major W[k][c]
    __shared__ float Xl[64 * 68];   // X[row][k], stride 68 (bank-spread)
    int tid = threadIdx.x;
    for (int i = tid; i < 4096; i += 256) Wl[i] = W[i];
    int row0 = blockIdx.x * 64;
    {
        int r = tid >> 6, c = tid & 63;
        #pragma unroll
        for (int p = 0; p < 16; ++p) {
            int rr = r + 4 * p;
            int grow = row0 + rr;
            Xl[rr * 68 + c] = (grow < N) ? X[(size_t)grow * 64 + c] : 0.0f;
        }
    }
    __syncthreads();
    int tc = tid & 15, tr = tid >> 4;
    float acc[4][4];
    #pragma unroll
    for (int i = 0; i < 4; ++i)
        #pragma unroll
        for (int j = 0; j < 4; ++j) acc[i][j] = 0.0f;

    #pragma unroll 8
    for (int k = 0; k < 64; ++k) {
        float4 wv = *(const float4*)&Wl[k * 64 + 4 * tc];
        float x0 = Xl[(4 * tr + 0) * 68 + k];
        float x1 = Xl[(4 * tr + 1) * 68 + k];
        float x2 = Xl[(4 * tr + 2) * 68 + k];
        float x3 = Xl[(4 * tr + 3) * 68 + k];
        acc[0][0] += x0 * wv.x; acc[0][1] += x0 * wv.y; acc[0][2] += x0 * wv.z; acc[0][3] += x0 * wv.w;
        acc[1][0] += x1 * wv.x; acc[1][1] += x1 * wv.y; acc[1][2] += x1 * wv.z; acc[1][3] += x1 * wv.w;
        acc[2][0] += x2 * wv.x; acc[2][1] += x2 * wv.y; acc[2][2] += x2 * wv.z; acc[2][3] += x2 * wv.w;
        acc[3][0] += x3 * wv.x; acc[3][1] += x3 * wv.y; acc[3][2] += x3 * wv.z; acc[3][3] += x3 * wv.w;
    }
    #pragma unroll
    for (int i = 0; i < 4; ++i) {
        int grow = row0 + 4 * tr + i;
        if (grow < N) {
            float4 st = make_float4(acc[i][0], acc[i][1], acc[i][2], acc[i][3]);
            *(float4*)&H[(size_t)grow * 64 + 4 * tc] = st;
        }
    }
}

// ---- aggregation: one wave per node; 4 edges/iter via 16-lane groups ----
// lane = 16*g + l  (g = edge slot within iteration, l = feature quad index)
// group g loads row H[src_{j+g}] as float4 (16 lanes x 16B = full 256B row).
// unroll 4 -> up to 16 rows in flight per wave. Cross-group xor-reduce at end.
__global__ __launch_bounds__(256) void agg_k(const float* __restrict__ H,
                                             const int* __restrict__ rowptr,
                                             const int2* __restrict__ csr,
                                             const float* __restrict__ dinv,
                                             const float* __restrict__ bias,
                                             float* __restrict__ out, int N) {
    int wave = (blockIdx.x * blockDim.x + threadIdx.x) >> 6;
    int lane = threadIdx.x & 63;
    if (wave >= N) return;
    int i = wave;
    int g = lane >> 4;        // 0..3  edge slot
    int l = lane & 15;        // 0..15 feature quad

    float di = dinv[i];
    // self loop (norm = dinv^2), counted once via group 0
    float4 acc;
    {
        float4 hv = *(const float4*)&H[(size_t)i * 64 + 4 * l];
        float s = (g == 0) ? (di * di) : 0.0f;
        acc.x = hv.x * s; acc.y = hv.y * s; acc.z = hv.z * s; acc.w = hv.w * s;
    }

    int e0 = rowptr[i], e1 = rowptr[i + 1];
    int e = e0;
    while (e < e1) {
        int nb = e1 - e;
        if (nb > 64) nb = 64;
        int2 m = (lane < nb) ? csr[e + lane] : make_int2(0, 0);   // pad: norm=0
        #pragma unroll 4
        for (int j = 0; j < nb; j += 4) {
            int   sl = j + g;                          // source lane (may hit pad)
            int   sj = __shfl(m.x, sl);
            float nj = __shfl(__int_as_float(m.y), sl);
            float4 hv = *(const float4*)&H[(size_t)sj * 64 + 4 * l];
            acc.x += hv.x * nj; acc.y += hv.y * nj;
            acc.z += hv.z * nj; acc.w += hv.w * nj;
        }
        e += nb;
    }

    // reduce across the 4 groups (xor 16, then 32) — all lanes end with sums
    acc.x += __shfl_xor(acc.x, 16); acc.y += __shfl_xor(acc.y, 16);
    acc.z += __shfl_xor(acc.z, 16); acc.w += __shfl_xor(acc.w, 16);
    acc.x += __shfl_xor(acc.x, 32); acc.y += __shfl_xor(acc.y, 32);
    acc.z += __shfl_xor(acc.z, 32); acc.w += __shfl_xor(acc.w, 32);

    if (g == 0) {
        float4 bv = *(const float4*)&bias[4 * l];
        float4 st;
        st.x = fmaxf(acc.x + bv.x, 0.0f);
        st.y = fmaxf(acc.y + bv.y, 0.0f);
        st.z = fmaxf(acc.z + bv.z, 0.0f);
        st.w = fmaxf(acc.w + bv.w, 0.0f);
        *(float4*)&out[(size_t)i * 64 + 4 * l] = st;
    }
}

// ---------------------------------------------------------------------------

extern "C" void kernel_launch(void* const* d_in, const int* in_sizes, int n_in,
                              void* d_out, int out_size, void* d_ws, size_t ws_size,
                              hipStream_t stream) {
    const float* x   = (const float*)d_in[0];
    const int*   ei  = (const int*)d_in[1];
    const float* ew  = (const float*)d_in[2];
    const float* W1  = (const float*)d_in[3];
    const float* b1  = (const float*)d_in[4];
    const float* W2  = (const float*)d_in[5];
    const float* b2  = (const float*)d_in[6];
    const float* W3  = (const float*)d_in[7];
    const float* b3  = (const float*)d_in[8];
    float* out = (float*)d_out;

    const int N = in_sizes[0] / 64;         // 100000
    const int E = in_sizes[1] / 2;          // 1200000
    const int* src = ei;
    const int* dst = ei + E;

    // ---- workspace carve-up (all 256B-aligned) ----
    char* p = (char*)d_ws;
    size_t off = 0;
    auto carve = [&](size_t bytes) -> void* {
        void* q = p + off;
        off += (bytes + 255) & ~(size_t)255;
        return q;
    };
    unsigned long long* packed = (unsigned long long*)carve((size_t)N * 8);
    float* dinv   = (float*)carve((size_t)N * 4);
    int*   tmp    = (int*)  carve((size_t)N * 4);
    int*   fill   = (int*)  carve((size_t)N * 4);
    int*   rowptr = (int*)  carve((size_t)(N + 1) * 4);
    int*   bsum   = (int*)  carve((size_t)1024 * 4);
    int2*  csr    = (int2*) carve((size_t)E * 8);
    float* Hbuf   = (float*)carve((size_t)N * 64 * 4);
    float* Abuf   = (float*)carve((size_t)N * 64 * 4);
    (void)ws_size;

    const int nB  = (N + 255) / 256;
    const int e4B = ((E + 3) / 4 + 255) / 256;      // 4 edges/thread
    const int nb  = (N + 1023) / 1024;              // scan blocks (98 for N=100K)
    const int gB  = (N + 63) / 64;                  // gemm blocks (64 rows each)
    const int aB  = (N * 64 + 255) / 256;           // agg blocks (4 waves each)

    // preprocessing
    init_k<<<nB, 256, 0, stream>>>(packed, fill, N);
    edge_pass_k<<<e4B, 256, 0, stream>>>(dst, ew, packed, E);
    scan_block_k<<<nb, 1024, 0, stream>>>(packed, dinv, tmp, bsum, N);
    scan_bsums_k<<<1, 1024, 0, stream>>>(bsum, nb, rowptr, N);
    scan_add_k<<<nb, 1024, 0, stream>>>(tmp, bsum, rowptr, N);
    fill_csr_k<<<e4B, 256, 0, stream>>>(src, dst, ew, dinv, rowptr, fill, csr, E);

    // layer 1: H = x @ W1 ; A = relu(agg(H) + b1)
    gemm64_k<<<gB, 256, 0, stream>>>(x, W1, Hbuf, N);
    agg_k<<<aB, 256, 0, stream>>>(Hbuf, rowptr, csr, dinv, b1, Abuf, N);
    // layer 2
    gemm64_k<<<gB, 256, 0, stream>>>(Abuf, W2, Hbuf, N);
    agg_k<<<aB, 256, 0, stream>>>(Hbuf, rowptr, csr, dinv, b2, Abuf, N);
    // layer 3 -> d_out
    gemm64_k<<<gB, 256, 0, stream>>>(Abuf, W3, Hbuf, N);
    agg_k<<<aB, 256, 0, stream>>>(Hbuf, rowptr, csr, dinv, b3, out, N);
}

// Round 8
// 412.840 us; speedup vs baseline: 1.4623x; 1.0926x over previous
//
#include <hip/hip_runtime.h>
#include <hip/hip_bf16.h>
#include <math.h>

// ---------------------------------------------------------------------------
// 3-layer GCN (PyG GCNConv semantics) on MI355X.
//   R2: packed u64 atomic per edge for degree (memory-side atomics halved).
//   R4: agg_k 16-lane-group float4 gathers (16 rows in flight; was latency-
//       bound at 83us/2.15TB/s).
//   R5: fill_csr atomics eliminated — edge_pass's packed atomicAdd RETURN
//       value carries the edge's rank in its dst bucket (bits 63:44).
//       fill_csr_k: pos = rowptr[dst] + rank[e], no atomics (was 85us,
//       WRITE_SIZE 78MB = 1.2M x 64B RMW).
// ---------------------------------------------------------------------------

#define MASK44 ((1ull << 44) - 1)

__global__ __launch_bounds__(256) void init_k(unsigned long long* packed, int N) {
    int i = blockIdx.x * blockDim.x + threadIdx.x;
    if (i < N) packed[i] = 0ull;
}

// one packed atomic per edge: (1<<44) + w * 2^32; old>>44 = rank within bucket
__global__ __launch_bounds__(256) void edge_pass_k(const int* __restrict__ dst,
                                                   const float* __restrict__ w,
                                                   unsigned long long* __restrict__ packed,
                                                   int* __restrict__ rank, int E) {
    int t = blockIdx.x * blockDim.x + threadIdx.x;
    int e = t * 4;
    if (e + 3 < E) {
        int4   d4 = *(const int4*)(dst + e);
        float4 w4 = *(const float4*)(w + e);
        unsigned long long o0 = atomicAdd(&packed[d4.x], (1ull << 44) + (unsigned long long)((double)w4.x * 4294967296.0));
        unsigned long long o1 = atomicAdd(&packed[d4.y], (1ull << 44) + (unsigned long long)((double)w4.y * 4294967296.0));
        unsigned long long o2 = atomicAdd(&packed[d4.z], (1ull << 44) + (unsigned long long)((double)w4.z * 4294967296.0));
        unsigned long long o3 = atomicAdd(&packed[d4.w], (1ull << 44) + (unsigned long long)((double)w4.w * 4294967296.0));
        *(int4*)(rank + e) = make_int4((int)(o0 >> 44), (int)(o1 >> 44),
                                       (int)(o2 >> 44), (int)(o3 >> 44));
    } else {
        for (int k = e; k < E; ++k) {
            unsigned long long o =
                atomicAdd(&packed[dst[k]], (1ull << 44) + (unsigned long long)((double)w[k] * 4294967296.0));
            rank[k] = (int)(o >> 44);
        }
    }
}

// block-level exclusive scan of counts (from packed) + fused dinv computation
__global__ __launch_bounds__(1024) void scan_block_k(const unsigned long long* __restrict__ packed,
                                                     float* __restrict__ dinv,
                                                     int* __restrict__ tmp,
                                                     int* __restrict__ bsum, int N) {
    __shared__ int sm[1024];
    int tid = threadIdx.x;
    int g = blockIdx.x * 1024 + tid;
    unsigned long long pk = (g < N) ? packed[g] : 0ull;
    int v = (int)(pk >> 44);
    if (g < N) {
        double deg = 1.0 + (double)(pk & MASK44) * (1.0 / 4294967296.0);   // >= 1 always
        dinv[g] = (float)(1.0 / sqrt(deg));
    }
    sm[tid] = v;
    __syncthreads();
    for (int off = 1; off < 1024; off <<= 1) {
        int t = (tid >= off) ? sm[tid - off] : 0;
        __syncthreads();
        sm[tid] += t;
        __syncthreads();
    }
    if (g < N) tmp[g] = sm[tid] - v;          // exclusive within block
    if (tid == 1023) bsum[blockIdx.x] = sm[1023];
}

// single-block parallel exclusive scan of the (<=1024) block sums
__global__ __launch_bounds__(1024) void scan_bsums_k(int* bsum, int nb, int* rowptr, int N) {
    __shared__ int sm[1024];
    int tid = threadIdx.x;
    int v = (tid < nb) ? bsum[tid] : 0;
    sm[tid] = v;
    __syncthreads();
    for (int off = 1; off < 1024; off <<= 1) {
        int t = (tid >= off) ? sm[tid - off] : 0;
        __syncthreads();
        sm[tid] += t;
        __syncthreads();
    }
    if (tid < nb) bsum[tid] = sm[tid] - v;
    if (tid == 1023) rowptr[N] = sm[1023];
}

__global__ __launch_bounds__(1024) void scan_add_k(const int* __restrict__ tmp,
                                                   const int* __restrict__ bsum,
                                                   int* __restrict__ rowptr, int N) {
    int g = blockIdx.x * 1024 + threadIdx.x;
    if (g < N) rowptr[g] = tmp[g] + bsum[blockIdx.x];
}

// CSR fill, atomic-free: pos = rowptr[dst] + rank (captured in edge_pass).
__global__ __launch_bounds__(256) void fill_csr_k(const int* __restrict__ src,
                                                  const int* __restrict__ dst,
                                                  const float* __restrict__ w,
                                                  const float* __restrict__ dinv,
                                                  const int* __restrict__ rowptr,
                                                  const int* __restrict__ rank,
                                                  int2* __restrict__ csr, int E) {
    int t = blockIdx.x * blockDim.x + threadIdx.x;
    int e = t * 4;
    if (e + 3 < E) {
        int4   s4 = *(const int4*)(src + e);
        int4   d4 = *(const int4*)(dst + e);
        int4   r4 = *(const int4*)(rank + e);
        float4 w4 = *(const float4*)(w + e);
        int p0 = rowptr[d4.x] + r4.x;
        int p1 = rowptr[d4.y] + r4.y;
        int p2 = rowptr[d4.z] + r4.z;
        int p3 = rowptr[d4.w] + r4.w;
        csr[p0] = make_int2(s4.x, __float_as_int(dinv[s4.x] * w4.x * dinv[d4.x]));
        csr[p1] = make_int2(s4.y, __float_as_int(dinv[s4.y] * w4.y * dinv[d4.y]));
        csr[p2] = make_int2(s4.z, __float_as_int(dinv[s4.z] * w4.z * dinv[d4.z]));
        csr[p3] = make_int2(s4.w, __float_as_int(dinv[s4.w] * w4.w * dinv[d4.w]));
    } else {
        for (int k = e; k < E; ++k) {
            int d = dst[k], s = src[k];
            int pos = rowptr[d] + rank[k];
            csr[pos] = make_int2(s, __float_as_int(dinv[s] * w[k] * dinv[d]));
        }
    }
}

// ---- GEMM: H[N,64] = X[N,64] @ W[64,64] (fp32, no MFMA on CDNA4) ----
__global__ __launch_bounds__(256) void gemm64_k(const float* __restrict__ X,
                                                const float* __restrict__ W,
                                                float* __restrict__ H, int N) {
    __shared__ float Wl[64 * 64];   // row-major W[k][c]
    __shared__ float Xl[64 * 68];   // X[row][k], stride 68 (bank-spread)
    int tid = threadIdx.x;
    for (int i = tid; i < 4096; i += 256) Wl[i] = W[i];
    int row0 = blockIdx.x * 64;
    {
        int r = tid >> 6, c = tid & 63;
        #pragma unroll
        for (int p = 0; p < 16; ++p) {
            int rr = r + 4 * p;
            int grow = row0 + rr;
            Xl[rr * 68 + c] = (grow < N) ? X[(size_t)grow * 64 + c] : 0.0f;
        }
    }
    __syncthreads();
    int tc = tid & 15, tr = tid >> 4;
    float acc[4][4];
    #pragma unroll
    for (int i = 0; i < 4; ++i)
        #pragma unroll
        for (int j = 0; j < 4; ++j) acc[i][j] = 0.0f;

    #pragma unroll 8
    for (int k = 0; k < 64; ++k) {
        float4 wv = *(const float4*)&Wl[k * 64 + 4 * tc];
        float x0 = Xl[(4 * tr + 0) * 68 + k];
        float x1 = Xl[(4 * tr + 1) * 68 + k];
        float x2 = Xl[(4 * tr + 2) * 68 + k];
        float x3 = Xl[(4 * tr + 3) * 68 + k];
        acc[0][0] += x0 * wv.x; acc[0][1] += x0 * wv.y; acc[0][2] += x0 * wv.z; acc[0][3] += x0 * wv.w;
        acc[1][0] += x1 * wv.x; acc[1][1] += x1 * wv.y; acc[1][2] += x1 * wv.z; acc[1][3] += x1 * wv.w;
        acc[2][0] += x2 * wv.x; acc[2][1] += x2 * wv.y; acc[2][2] += x2 * wv.z; acc[2][3] += x2 * wv.w;
        acc[3][0] += x3 * wv.x; acc[3][1] += x3 * wv.y; acc[3][2] += x3 * wv.z; acc[3][3] += x3 * wv.w;
    }
    #pragma unroll
    for (int i = 0; i < 4; ++i) {
        int grow = row0 + 4 * tr + i;
        if (grow < N) {
            float4 st = make_float4(acc[i][0], acc[i][1], acc[i][2], acc[i][3]);
            *(float4*)&H[(size_t)grow * 64 + 4 * tc] = st;
        }
    }
}

// ---- aggregation: one wave per node; 4 edges/iter via 16-lane groups ----
__global__ __launch_bounds__(256) void agg_k(const float* __restrict__ H,
                                             const int* __restrict__ rowptr,
                                             const int2* __restrict__ csr,
                                             const float* __restrict__ dinv,
                                             const float* __restrict__ bias,
                                             float* __restrict__ out, int N) {
    int wave = (blockIdx.x * blockDim.x + threadIdx.x) >> 6;
    int lane = threadIdx.x & 63;
    if (wave >= N) return;
    int i = wave;
    int g = lane >> 4;        // 0..3  edge slot
    int l = lane & 15;        // 0..15 feature quad

    float di = dinv[i];
    // self loop (norm = dinv^2), counted once via group 0
    float4 acc;
    {
        float4 hv = *(const float4*)&H[(size_t)i * 64 + 4 * l];
        float s = (g == 0) ? (di * di) : 0.0f;
        acc.x = hv.x * s; acc.y = hv.y * s; acc.z = hv.z * s; acc.w = hv.w * s;
    }

    int e0 = rowptr[i], e1 = rowptr[i + 1];
    int e = e0;
    while (e < e1) {
        int nb = e1 - e;
        if (nb > 64) nb = 64;
        int2 m = (lane < nb) ? csr[e + lane] : make_int2(0, 0);   // pad: norm=0
        #pragma unroll 4
        for (int j = 0; j < nb; j += 4) {
            int   sl = j + g;                          // source lane (may hit pad)
            int   sj = __shfl(m.x, sl);
            float nj = __shfl(__int_as_float(m.y), sl);
            float4 hv = *(const float4*)&H[(size_t)sj * 64 + 4 * l];
            acc.x += hv.x * nj; acc.y += hv.y * nj;
            acc.z += hv.z * nj; acc.w += hv.w * nj;
        }
        e += nb;
    }

    // reduce across the 4 groups (xor 16, then 32)
    acc.x += __shfl_xor(acc.x, 16); acc.y += __shfl_xor(acc.y, 16);
    acc.z += __shfl_xor(acc.z, 16); acc.w += __shfl_xor(acc.w, 16);
    acc.x += __shfl_xor(acc.x, 32); acc.y += __shfl_xor(acc.y, 32);
    acc.z += __shfl_xor(acc.z, 32); acc.w += __shfl_xor(acc.w, 32);

    if (g == 0) {
        float4 bv = *(const float4*)&bias[4 * l];
        float4 st;
        st.x = fmaxf(acc.x + bv.x, 0.0f);
        st.y = fmaxf(acc.y + bv.y, 0.0f);
        st.z = fmaxf(acc.z + bv.z, 0.0f);
        st.w = fmaxf(acc.w + bv.w, 0.0f);
        *(float4*)&out[(size_t)i * 64 + 4 * l] = st;
    }
}

// ---------------------------------------------------------------------------

extern "C" void kernel_launch(void* const* d_in, const int* in_sizes, int n_in,
                              void* d_out, int out_size, void* d_ws, size_t ws_size,
                              hipStream_t stream) {
    const float* x   = (const float*)d_in[0];
    const int*   ei  = (const int*)d_in[1];
    const float* ew  = (const float*)d_in[2];
    const float* W1  = (const float*)d_in[3];
    const float* b1  = (const float*)d_in[4];
    const float* W2  = (const float*)d_in[5];
    const float* b2  = (const float*)d_in[6];
    const float* W3  = (const float*)d_in[7];
    const float* b3  = (const float*)d_in[8];
    float* out = (float*)d_out;

    const int N = in_sizes[0] / 64;         // 100000
    const int E = in_sizes[1] / 2;          // 1200000
    const int* src = ei;
    const int* dst = ei + E;

    // ---- workspace carve-up (all 256B-aligned) ----
    char* p = (char*)d_ws;
    size_t off = 0;
    auto carve = [&](size_t bytes) -> void* {
        void* q = p + off;
        off += (bytes + 255) & ~(size_t)255;
        return q;
    };
    unsigned long long* packed = (unsigned long long*)carve((size_t)N * 8);
    float* dinv   = (float*)carve((size_t)N * 4);
    int*   tmp    = (int*)  carve((size_t)N * 4);
    int*   rowptr = (int*)  carve((size_t)(N + 1) * 4);
    int*   bsum   = (int*)  carve((size_t)1024 * 4);
    int*   rank   = (int*)  carve((size_t)E * 4);
    int2*  csr    = (int2*) carve((size_t)E * 8);
    float* Hbuf   = (float*)carve((size_t)N * 64 * 4);
    float* Abuf   = (float*)carve((size_t)N * 64 * 4);
    (void)ws_size;

    const int nB  = (N + 255) / 256;
    const int e4B = ((E + 3) / 4 + 255) / 256;      // 4 edges/thread
    const int nb  = (N + 1023) / 1024;              // scan blocks (98 for N=100K)
    const int gB  = (N + 63) / 64;                  // gemm blocks (64 rows each)
    const int aB  = (N * 64 + 255) / 256;           // agg blocks (4 waves each)

    // preprocessing
    init_k<<<nB, 256, 0, stream>>>(packed, N);
    edge_pass_k<<<e4B, 256, 0, stream>>>(dst, ew, packed, rank, E);
    scan_block_k<<<nb, 1024, 0, stream>>>(packed, dinv, tmp, bsum, N);
    scan_bsums_k<<<1, 1024, 0, stream>>>(bsum, nb, rowptr, N);
    scan_add_k<<<nb, 1024, 0, stream>>>(tmp, bsum, rowptr, N);
    fill_csr_k<<<e4B, 256, 0, stream>>>(src, dst, ew, dinv, rowptr, rank, csr, E);

    // layer 1: H = x @ W1 ; A = relu(agg(H) + b1)
    gemm64_k<<<gB, 256, 0, stream>>>(x, W1, Hbuf, N);
    agg_k<<<aB, 256, 0, stream>>>(Hbuf, rowptr, csr, dinv, b1, Abuf, N);
    // layer 2
    gemm64_k<<<gB, 256, 0, stream>>>(Abuf, W2, Hbuf, N);
    agg_k<<<aB, 256, 0, stream>>>(Hbuf, rowptr, csr, dinv, b2, Abuf, N);
    // layer 3 -> d_out
    gemm64_k<<<gB, 256, 0, stream>>>(Abuf, W3, Hbuf, N);
    agg_k<<<aB, 256, 0, stream>>>(Hbuf, rowptr, csr, dinv, b3, out, N);
}